// Round 6
// baseline (336.016 us; speedup 1.0000x reference)
//
#include <hip/hip_runtime.h>
#include <hip/hip_bf16.h>
#include <stdint.h>

typedef __attribute__((ext_vector_type(8))) short short8;
typedef __attribute__((ext_vector_type(4))) float f32x4;
typedef unsigned short ushort_t;

#define MFMA16(a, b, c) __builtin_amdgcn_mfma_f32_16x16x32_bf16((a), (b), (c), 0, 0, 0)
#define EXP2F(x) __builtin_amdgcn_exp2f(x)
#define BAR() __builtin_amdgcn_s_barrier()

// B=8 S=1024 D=1024 H=16 hd=64; M = B*S = 8192; N = 3*D = 3072; K = 1024

__device__ __forceinline__ float bf2f(unsigned short u) {
    union { unsigned int i; float f; } x; x.i = ((unsigned int)u) << 16; return x.f;
}
__device__ __forceinline__ unsigned short f2bf(float f) {
    union { float f; unsigned int i; } x; x.f = f;
    unsigned int i = x.i;
    i = i + 0x7FFFu + ((i >> 16) & 1u);   // RNE
    return (unsigned short)(i >> 16);
}
__device__ __forceinline__ unsigned int pack2(float a, float b) {
    return (unsigned int)f2bf(a) | ((unsigned int)f2bf(b) << 16);
}
__device__ __forceinline__ void glds16(const void* gsrc, void* ldst) {
    __builtin_amdgcn_global_load_lds(
        (const __attribute__((address_space(1))) unsigned int*)gsrc,
        (__attribute__((address_space(3))) unsigned int*)ldst, 16, 0, 0);
}

// ---------------- kernel 1: fused prep — bf16 convert of H,W + lora lo ----------------
// 256-thread blocks: each of 4 waves does one logical 64-thread block's work.
__global__ __launch_bounds__(256) void prep_kernel(
    const float* __restrict__ hidden,   // (8192,1024)
    const float* __restrict__ W,        // (3072,1024)
    const float* __restrict__ loraA,    // (5,4,1024)
    const int* __restrict__ adapter_mask,
    ushort_t* __restrict__ Hb,
    ushort_t* __restrict__ Wb,
    float4* __restrict__ lo)
{
    int tid = threadIdx.x;
    int blk = blockIdx.x * 4 + (tid >> 6);   // 0..11263
    int lane = tid & 63;
    if (blk < 8192) {
        int b = blk >> 10;
        int a = adapter_mask[b];
        const float* hp = hidden + (size_t)blk * 1024 + lane * 16;
        float hv[16];
        for (int j = 0; j < 16; ++j) hv[j] = hp[j];
        uint4 p0, p1;
        p0.x = pack2(hv[0], hv[1]);  p0.y = pack2(hv[2], hv[3]);
        p0.z = pack2(hv[4], hv[5]);  p0.w = pack2(hv[6], hv[7]);
        p1.x = pack2(hv[8], hv[9]);  p1.y = pack2(hv[10], hv[11]);
        p1.z = pack2(hv[12], hv[13]); p1.w = pack2(hv[14], hv[15]);
        uint4* hd = (uint4*)(Hb + (size_t)blk * 1024 + lane * 16);
        hd[0] = p0; hd[1] = p1;
        const float* Ap = loraA + (size_t)a * 4096 + lane * 16;
        float acc[4];
        for (int r = 0; r < 4; ++r) {
            const float* ap = Ap + r * 1024;
            float s = 0.f;
            for (int j = 0; j < 16; ++j) s += hv[j] * ap[j];
            acc[r] = s;
        }
        for (int off = 32; off > 0; off >>= 1)
            for (int r = 0; r < 4; ++r) acc[r] += __shfl_xor(acc[r], off);
        if (lane == 0) lo[blk] = make_float4(acc[0], acc[1], acc[2], acc[3]);
    } else {
        int row = blk - 8192;     // 0..3071
        const float* wp = W + (size_t)row * 1024 + lane * 16;
        float wv[16];
        for (int j = 0; j < 16; ++j) wv[j] = wp[j];
        uint4 p0, p1;
        p0.x = pack2(wv[0], wv[1]);  p0.y = pack2(wv[2], wv[3]);
        p0.z = pack2(wv[4], wv[5]);  p0.w = pack2(wv[6], wv[7]);
        p1.x = pack2(wv[8], wv[9]);  p1.y = pack2(wv[10], wv[11]);
        p1.z = pack2(wv[12], wv[13]); p1.w = pack2(wv[14], wv[15]);
        uint4* wd = (uint4*)(Wb + (size_t)row * 1024 + lane * 16);
        wd[0] = p0; wd[1] = p1;
    }
}

// ---------------- kernel 2: qkv GEMM (round-4 version, best measured) ----------
__global__ __launch_bounds__(512, 2) void qkv_gemm_kernel(
    const ushort_t* __restrict__ Hb,   // (8192,1024) bf16
    const ushort_t* __restrict__ Wb,   // (3072,1024) bf16
    const float* __restrict__ bias,    // (3072)
    const float4* __restrict__ lo,     // (8192)
    const float* __restrict__ loraB,   // (5,3072,4)
    const int* __restrict__ adapter_mask, // (8)
    const float* __restrict__ cosp,    // (8,1024,64)
    const float* __restrict__ sinp,
    ushort_t* __restrict__ qw,
    ushort_t* __restrict__ kw,
    ushort_t* __restrict__ vt)
{
    __shared__ __align__(16) ushort_t As[2][16384];   // 64 KB
    __shared__ __align__(16) ushort_t Bs[2][16384];   // 64 KB
    int tid = threadIdx.x;
    int wave = tid >> 6, lane = tid & 63, quad = lane >> 4, l16 = lane & 15;
    int wm = wave >> 2, wn = wave & 3;               // 2M x 4N

    // bijective XCD swizzle: 384 blocks = 8 * 48
    int wg = (blockIdx.x & 7) * 48 + (blockIdx.x >> 3);
    int bx = wg % 12, by = wg / 12;
    int n0 = bx * 256;
    int m0 = by * 256;

    int r_ = tid >> 3, c_ = (tid & 7) ^ (r_ & 7);
    const ushort_t* pA0 = Hb + (size_t)(m0 +   0 + r_) * 1024 + c_ * 8;
    const ushort_t* pA1 = Hb + (size_t)(m0 +  64 + r_) * 1024 + c_ * 8;
    const ushort_t* pA2 = Hb + (size_t)(m0 + 128 + r_) * 1024 + c_ * 8;
    const ushort_t* pA3 = Hb + (size_t)(m0 + 192 + r_) * 1024 + c_ * 8;
    const ushort_t* pB0 = Wb + (size_t)(n0 +   0 + r_) * 1024 + c_ * 8;
    const ushort_t* pB1 = Wb + (size_t)(n0 +  64 + r_) * 1024 + c_ * 8;
    const ushort_t* pB2 = Wb + (size_t)(n0 + 128 + r_) * 1024 + c_ * 8;
    const ushort_t* pB3 = Wb + (size_t)(n0 + 192 + r_) * 1024 + c_ * 8;
    char* stA0 = (char*)&As[0][0] + wave * 1024;     // + buf*32768 + unit*8192
    char* stB0 = (char*)&Bs[0][0] + wave * 1024;

    f32x4 acc[8][4];
#pragma unroll
    for (int i = 0; i < 8; ++i)
#pragma unroll
        for (int j = 0; j < 4; ++j) acc[i][j] = (f32x4)0.f;

    // prologue issue order (vmcnt ledger): B(0) x4, A(0) x4, B(1) x4
    glds16(pB0, stB0);          glds16(pB1, stB0 + 8192);
    glds16(pB2, stB0 + 16384);  glds16(pB3, stB0 + 24576);
    glds16(pA0, stA0);          glds16(pA1, stA0 + 8192);
    glds16(pA2, stA0 + 16384);  glds16(pA3, stA0 + 24576);
    glds16(pB0 + 64, stB0 + 32768);          glds16(pB1 + 64, stB0 + 32768 + 8192);
    glds16(pB2 + 64, stB0 + 32768 + 16384);  glds16(pB3 + 64, stB0 + 32768 + 24576);

#pragma unroll 2
    for (int t = 0; t < 16; ++t) {
        int cur = t & 1;
        const char* rdA = (const char*)&As[0][0] + cur * 32768;
        const char* rdB = (const char*)&Bs[0][0] + cur * 32768;
        char* sA = stA0 + (cur ^ 1) * 32768;   // A(t+1) -> other buffer
        char* sB = stB0 + cur * 32768;         // B(t+2) -> buf cur (free after B reads)
        int kA = (t + 1) << 6;
        int kB = (t + 2) << 6;

        // ---- entry: A(t),B(t) forced complete; B(t+1)'s 4 loads stay in flight
        if (t < 15) { asm volatile("s_waitcnt vmcnt(4)" ::: "memory"); }
        else        { asm volatile("s_waitcnt vmcnt(0)" ::: "memory"); }
        BAR();
        if (t < 15) {
            glds16(pA0 + kA, sA);          glds16(pA1 + kA, sA + 8192);
            glds16(pA2 + kA, sA + 16384);  glds16(pA3 + kA, sA + 24576);
        }
        short8 bfr[4][2];
#pragma unroll
        for (int ni = 0; ni < 4; ++ni) {
            int rb = ni * 16 + l16;
            bfr[ni][0] = *(const short8*)(rdB + wn * 8192 + (rb * 8 + ((quad    ) ^ (rb & 7))) * 16);
            bfr[ni][1] = *(const short8*)(rdB + wn * 8192 + (rb * 8 + ((quad + 4) ^ (rb & 7))) * 16);
        }
        asm volatile("s_waitcnt lgkmcnt(0)" ::: "memory");   // only B reads outstanding
        BAR();                                               // B region of buf cur now free
        if (t < 14) {
            glds16(pB0 + kB, sB);          glds16(pB1 + kB, sB + 8192);
            glds16(pB2 + kB, sB + 16384);  glds16(pB3 + kB, sB + 24576);
        }
        // A reads + MFMA, no barriers — compiler overlaps read latency with MFMAs
        __builtin_amdgcn_s_setprio(1);
#pragma unroll
        for (int mi = 0; mi < 8; ++mi) {
            int u = wm * 2 + (mi >> 2);
            int rr = (mi & 3) * 16 + l16;
            short8 a0 = *(const short8*)(rdA + u * 8192 + (rr * 8 + ((quad    ) ^ (rr & 7))) * 16);
            short8 a1 = *(const short8*)(rdA + u * 8192 + (rr * 8 + ((quad + 4) ^ (rr & 7))) * 16);
            acc[mi][0] = MFMA16(a0, bfr[0][0], acc[mi][0]);
            acc[mi][1] = MFMA16(a0, bfr[1][0], acc[mi][1]);
            acc[mi][2] = MFMA16(a0, bfr[2][0], acc[mi][2]);
            acc[mi][3] = MFMA16(a0, bfr[3][0], acc[mi][3]);
            acc[mi][0] = MFMA16(a1, bfr[0][1], acc[mi][0]);
            acc[mi][1] = MFMA16(a1, bfr[1][1], acc[mi][1]);
            acc[mi][2] = MFMA16(a1, bfr[2][1], acc[mi][2]);
            acc[mi][3] = MFMA16(a1, bfr[3][1], acc[mi][3]);
        }
        __builtin_amdgcn_s_setprio(0);
    }

    // epilogue: bias + lora + rope + scatter
    int t_qkv = n0 >> 10;        // 0=q 1=k 2=v, block-uniform (256 | 1024)
    int b = m0 >> 10;            // block-uniform
    int a_idx = adapter_mask[b];
    float bi[4], bb[4][4];
    int cpos[4], chh[4];
#pragma unroll
    for (int ni = 0; ni < 4; ++ni) {
        int c = n0 + wn * 64 + ni * 16 + l16;
        bi[ni] = bias[c];
        const float* Bp = loraB + ((size_t)a_idx * 3072 + c) * 4;
        bb[ni][0] = Bp[0]; bb[ni][1] = Bp[1]; bb[ni][2] = Bp[2]; bb[ni][3] = Bp[3];
        cpos[ni] = c & 63; chh[ni] = (c >> 6) & 15;
    }
#pragma unroll
    for (int mi = 0; mi < 8; ++mi) {
        float vals[4][4];   // [r][ni]
        int mrow0 = m0 + wm * 128 + mi * 16 + quad * 4;
#pragma unroll
        for (int r = 0; r < 4; ++r) {
            float4 lov = lo[mrow0 + r];
#pragma unroll
            for (int ni = 0; ni < 4; ++ni)
                vals[r][ni] = acc[mi][ni][r] + bi[ni]
                      + 0.25f * (lov.x * bb[ni][0] + lov.y * bb[ni][1]
                               + lov.z * bb[ni][2] + lov.w * bb[ni][3]);
        }
        int s0 = mrow0 & 1023;
        if (t_qkv < 2) {
#pragma unroll
            for (int r = 0; r < 4; ++r) {
                int s = s0 + r;
                size_t cb = ((size_t)b * 1024 + s) * 64;
                float cA = cosp[cb + l16],      sA_ = sinp[cb + l16];
                float cB = cosp[cb + 16 + l16], sB_ = sinp[cb + 16 + l16];
                float w0 = vals[r][0] * cA - vals[r][2] * sA_;
                float w2 = vals[r][2] * cA + vals[r][0] * sA_;
                float w1 = vals[r][1] * cB - vals[r][3] * sB_;
                float w3 = vals[r][3] * cB + vals[r][1] * sB_;
                float v[4] = {w0, w1, w2, w3};
#pragma unroll
                for (int ni = 0; ni < 4; ++ni) {
                    size_t bh = (size_t)b * 16 + chh[ni];
                    ushort_t ob = f2bf(v[ni]);
                    if (t_qkv == 0) qw[(bh * 1024 + s) * 64 + cpos[ni]] = ob;
                    else            kw[(bh * 1024 + s) * 64 + cpos[ni]] = ob;
                }
            }
        } else {
#pragma unroll
            for (int ni = 0; ni < 4; ++ni) {
                uint2 pk;
                pk.x = pack2(vals[0][ni], vals[1][ni]);
                pk.y = pack2(vals[2][ni], vals[3][ni]);
                size_t bh = (size_t)b * 16 + chh[ni];
                *(uint2*)&vt[(bh * 64 + cpos[ni]) * 1024 + s0] = pk;
            }
        }
    }
}

// ---------------- kernel 3: attention — UNSTAGED K/V (m169 pattern: S=1024 K/V is ----
// L2-resident; all 8 q-tile blocks of a bh land on the same XCD since id%8==bh%8).
// Direct global 16B fragment loads for K and V; zero barriers in the main loop;
// waves fully independent. LDS = Ps + mask only (22 KB) -> ~4 waves/SIMD TLP.
__global__ __launch_bounds__(256) void attn_kernel(
    const ushort_t* __restrict__ qw,   // (B,H,S,hd) bf16 (rope applied)
    const ushort_t* __restrict__ kw,   // (B,H,S,hd) bf16 (rope applied)
    const ushort_t* __restrict__ vt,   // (B,H,hd,S) bf16
    const float* __restrict__ mask,    // (B,1,1,S) f32
    float* __restrict__ out)           // (B,S,H*hd) f32
{
    __shared__ __align__(16) ushort_t Ps[4][32][72];  // per-wave, 18KB
    __shared__ float mlds[1024];                      // 4KB
    const float KSCALE = 0.125f * 1.44269504f;
    int tid = threadIdx.x;
    int wave = tid >> 6, lane = tid & 63, quad = lane >> 4, l16 = lane & 15;
    int id = blockIdx.x;
    int qt = id >> 7;             // 0..7
    int bh = id & 127;            // 0..127
    int b = bh >> 4, h = bh & 15;
    size_t base = (size_t)bh * 65536;
    int q0 = qt * 128 + wave * 32;

    for (int i = tid; i < 1024; i += 256) mlds[i] = mask[b * 1024 + i] * 1.44269504f;

    const ushort_t* kbase = kw + base;
    const ushort_t* vbase = vt + base;

    short8 qf[2][2];
    for (int mt = 0; mt < 2; ++mt)
        for (int kt = 0; kt < 2; ++kt)
            qf[mt][kt] = *(const short8*)(qw + base + (size_t)(q0 + mt * 16 + l16) * 64 + kt * 32 + quad * 8);

    f32x4 oacc[2][4], sum_acc[2];
    for (int mt = 0; mt < 2; ++mt) {
        sum_acc[mt] = (f32x4)0.f;
        for (int nt = 0; nt < 4; ++nt) oacc[mt][nt] = (f32x4)0.f;
    }

    short8 ones;
    for (int j = 0; j < 8; ++j) ones[j] = (short)0x3F80;   // bf16 1.0

    __syncthreads();   // mlds visible to all waves (one-time)

    for (int it = 0; it < 16; ++it) {
        int kt0 = it * 64;
        // K fragments direct from global (L2-resident, per-lane 16B contiguous)
        short8 kf[4][2];
        for (int nt = 0; nt < 4; ++nt)
            for (int kt = 0; kt < 2; ++kt)
                kf[nt][kt] = *(const short8*)(kbase
                    + (size_t)(kt0 + nt * 16 + l16) * 64 + kt * 32 + quad * 8);
        f32x4 sacc[2][4];
        for (int mt = 0; mt < 2; ++mt)
            for (int nt = 0; nt < 4; ++nt) {
                f32x4 z = (f32x4)0.f;
                z = MFMA16(qf[mt][0], kf[nt][0], z);
                z = MFMA16(qf[mt][1], kf[nt][1], z);
                sacc[mt][nt] = z;
            }
        float mv[4];
        for (int nt = 0; nt < 4; ++nt) mv[nt] = mlds[kt0 + nt * 16 + l16];
        // P = exp2(scale*S + mask'); exact (scores bounded, fp32-safe)
        for (int mt = 0; mt < 2; ++mt)
            for (int nt = 0; nt < 4; ++nt)
                for (int r = 0; r < 4; ++r) {
                    float p = EXP2F(sacc[mt][nt][r] * KSCALE + mv[nt]);
                    Ps[wave][mt * 16 + quad * 4 + r][nt * 16 + l16] = f2bf(p);
                }
        short8 pf[2][2];
        for (int mt = 0; mt < 2; ++mt)
            for (int kt = 0; kt < 2; ++kt)
                pf[mt][kt] = *(const short8*)&Ps[wave][mt * 16 + l16][kt * 32 + quad * 8];
        // V fragments direct from global (vt is (bh, hd, S): per-lane 16B contiguous in S)
        short8 vf[4][2];
        for (int nt = 0; nt < 4; ++nt)
            for (int kt = 0; kt < 2; ++kt)
                vf[nt][kt] = *(const short8*)(vbase
                    + (size_t)(nt * 16 + l16) * 1024 + kt0 + kt * 32 + quad * 8);
        for (int mt = 0; mt < 2; ++mt) {
            for (int nt = 0; nt < 4; ++nt) {
                oacc[mt][nt] = MFMA16(pf[mt][0], vf[nt][0], oacc[mt][nt]);
                oacc[mt][nt] = MFMA16(pf[mt][1], vf[nt][1], oacc[mt][nt]);
            }
            sum_acc[mt] = MFMA16(pf[mt][0], ones, sum_acc[mt]);
            sum_acc[mt] = MFMA16(pf[mt][1], ones, sum_acc[mt]);
        }
    }

    for (int mt = 0; mt < 2; ++mt) {
        for (int r = 0; r < 4; ++r) {
            float inv = 1.f / sum_acc[mt][r];
            int s = q0 + mt * 16 + quad * 4 + r;
            size_t ob = ((size_t)b * 1024 + s) * 1024 + h * 64;
            for (int nt = 0; nt < 4; ++nt)
                out[ob + nt * 16 + l16] = oacc[mt][nt][r] * inv;
        }
    }
}

extern "C" void kernel_launch(void* const* d_in, const int* in_sizes, int n_in,
                              void* d_out, int out_size, void* d_ws, size_t ws_size,
                              hipStream_t stream)
{
    const float* hidden = (const float*)d_in[0];
    const float* mask   = (const float*)d_in[1];
    const float* cosp   = (const float*)d_in[2];
    const float* sinp   = (const float*)d_in[3];
    const int* adapter_mask = (const int*)d_in[4];
    const float* W      = (const float*)d_in[5];
    const float* bias   = (const float*)d_in[6];
    const float* loraA  = (const float*)d_in[7];
    const float* loraB  = (const float*)d_in[8];
    float* out = (float*)d_out;

    char* ws = (char*)d_ws;
    float4* lo = (float4*)ws;                                  // 128 KB
    ushort_t* qw = (ushort_t*)(ws + (1 << 20));                // 16 MB each
    ushort_t* kw = qw + (size_t)8 * 16 * 1024 * 64;
    ushort_t* vt = kw + (size_t)8 * 16 * 1024 * 64;            // total 49 MB (proven fits)

    ushort_t* Hb = (ushort_t*)d_out;                           // 16 MB
    ushort_t* Wb = Hb + (size_t)8192 * 1024;                   // 6 MB

    prep_kernel<<<2816, 256, 0, stream>>>(hidden, W, loraA, adapter_mask, Hb, Wb, lo);
    qkv_gemm_kernel<<<384, 512, 0, stream>>>(Hb, Wb, bias, lo, loraB, adapter_mask,
                                             cosp, sinp, qw, kw, vt);
    attn_kernel<<<1024, 256, 0, stream>>>(qw, kw, vt, mask, out);
}

// Round 7
// 245.897 us; speedup vs baseline: 1.3665x; 1.3665x over previous
//
#include <hip/hip_runtime.h>
#include <hip/hip_bf16.h>
#include <stdint.h>

typedef __attribute__((ext_vector_type(8))) short short8;
typedef __attribute__((ext_vector_type(4))) float f32x4;
typedef unsigned short ushort_t;

#define MFMA16(a, b, c) __builtin_amdgcn_mfma_f32_16x16x32_bf16((a), (b), (c), 0, 0, 0)
#define EXP2F(x) __builtin_amdgcn_exp2f(x)
#define BAR() __builtin_amdgcn_s_barrier()

// B=8 S=1024 D=1024 H=16 hd=64; M = B*S = 8192; N = 3*D = 3072; K = 1024

__device__ __forceinline__ float bf2f(unsigned short u) {
    union { unsigned int i; float f; } x; x.i = ((unsigned int)u) << 16; return x.f;
}
__device__ __forceinline__ unsigned short f2bf(float f) {
    union { float f; unsigned int i; } x; x.f = f;
    unsigned int i = x.i;
    i = i + 0x7FFFu + ((i >> 16) & 1u);   // RNE
    return (unsigned short)(i >> 16);
}
__device__ __forceinline__ unsigned int pack2(float a, float b) {
    return (unsigned int)f2bf(a) | ((unsigned int)f2bf(b) << 16);
}
__device__ __forceinline__ void glds16(const void* gsrc, void* ldst) {
    __builtin_amdgcn_global_load_lds(
        (const __attribute__((address_space(1))) unsigned int*)gsrc,
        (__attribute__((address_space(3))) unsigned int*)ldst, 16, 0, 0);
}

// ---------------- kernel 1: fused prep v2 — per-instruction coalesced ----------------
// One wave per row. Lane reads float4 at chunk*1KB + lane*16B: every load
// instruction covers 1KB contiguous (was: lane*64B stride -> 32 line-transactions
// per instr). Stores uint2 at chunk*512B + lane*8B: 512B contiguous per instr.
// Output layout bit-identical to v1 (Hb[row][k] = bf16(hidden[row][k])).
__global__ __launch_bounds__(256) void prep_kernel(
    const float* __restrict__ hidden,   // (8192,1024)
    const float* __restrict__ W,        // (3072,1024)
    const float* __restrict__ loraA,    // (5,4,1024)
    const int* __restrict__ adapter_mask,
    ushort_t* __restrict__ Hb,
    ushort_t* __restrict__ Wb,
    float4* __restrict__ lo)
{
    int tid = threadIdx.x;
    int wave = tid >> 6, lane = tid & 63;
    int row = blockIdx.x * 4 + wave;     // 0..11263
    if (row < 8192) {
        int b = row >> 10;
        int a = adapter_mask[b];
        const float4* hp = (const float4*)(hidden + (size_t)row * 1024);
        float4 hv[4];
#pragma unroll
        for (int c = 0; c < 4; ++c) hv[c] = hp[c * 64 + lane];
#pragma unroll
        for (int c = 0; c < 4; ++c) {
            uint2 pk;
            pk.x = pack2(hv[c].x, hv[c].y);
            pk.y = pack2(hv[c].z, hv[c].w);
            *(uint2*)(Hb + (size_t)row * 1024 + c * 256 + lane * 4) = pk;
        }
        const float4* Ap = (const float4*)(loraA + (size_t)a * 4096);
        float acc[4];
#pragma unroll
        for (int r = 0; r < 4; ++r) {
            float s = 0.f;
#pragma unroll
            for (int c = 0; c < 4; ++c) {
                float4 av = Ap[r * 64 + c * 16 + (lane >> 2) * 1 + 0];
                // NOTE: replaced below — see correct indexing
                s += 0.f * av.x;
            }
            acc[r] = s;
        }
        // correct lora dot (A row r, same element positions as hv):
#pragma unroll
        for (int r = 0; r < 4; ++r) {
            float s = 0.f;
#pragma unroll
            for (int c = 0; c < 4; ++c) {
                float4 av = Ap[(size_t)r * 256 + c * 64 + lane];
                s += hv[c].x * av.x + hv[c].y * av.y + hv[c].z * av.z + hv[c].w * av.w;
            }
            acc[r] = s;
        }
        for (int off = 32; off > 0; off >>= 1)
#pragma unroll
            for (int r = 0; r < 4; ++r) acc[r] += __shfl_xor(acc[r], off);
        if (lane == 0) lo[row] = make_float4(acc[0], acc[1], acc[2], acc[3]);
    } else {
        int rw = row - 8192;             // 0..3071
        const float4* wp = (const float4*)(W + (size_t)rw * 1024);
        float4 wv[4];
#pragma unroll
        for (int c = 0; c < 4; ++c) wv[c] = wp[c * 64 + lane];
#pragma unroll
        for (int c = 0; c < 4; ++c) {
            uint2 pk;
            pk.x = pack2(wv[c].x, wv[c].y);
            pk.y = pack2(wv[c].z, wv[c].w);
            *(uint2*)(Wb + (size_t)rw * 1024 + c * 256 + lane * 4) = pk;
        }
    }
}

// ---------------- kernel 2: qkv GEMM (round-4 version, best measured) ----------
__global__ __launch_bounds__(512, 2) void qkv_gemm_kernel(
    const ushort_t* __restrict__ Hb,   // (8192,1024) bf16
    const ushort_t* __restrict__ Wb,   // (3072,1024) bf16
    const float* __restrict__ bias,    // (3072)
    const float4* __restrict__ lo,     // (8192)
    const float* __restrict__ loraB,   // (5,3072,4)
    const int* __restrict__ adapter_mask, // (8)
    const float* __restrict__ cosp,    // (8,1024,64)
    const float* __restrict__ sinp,
    ushort_t* __restrict__ qw,
    ushort_t* __restrict__ kw,
    ushort_t* __restrict__ vt)
{
    __shared__ __align__(16) ushort_t As[2][16384];   // 64 KB
    __shared__ __align__(16) ushort_t Bs[2][16384];   // 64 KB
    int tid = threadIdx.x;
    int wave = tid >> 6, lane = tid & 63, quad = lane >> 4, l16 = lane & 15;
    int wm = wave >> 2, wn = wave & 3;               // 2M x 4N

    // bijective XCD swizzle: 384 blocks = 8 * 48
    int wg = (blockIdx.x & 7) * 48 + (blockIdx.x >> 3);
    int bx = wg % 12, by = wg / 12;
    int n0 = bx * 256;
    int m0 = by * 256;

    int r_ = tid >> 3, c_ = (tid & 7) ^ (r_ & 7);
    const ushort_t* pA0 = Hb + (size_t)(m0 +   0 + r_) * 1024 + c_ * 8;
    const ushort_t* pA1 = Hb + (size_t)(m0 +  64 + r_) * 1024 + c_ * 8;
    const ushort_t* pA2 = Hb + (size_t)(m0 + 128 + r_) * 1024 + c_ * 8;
    const ushort_t* pA3 = Hb + (size_t)(m0 + 192 + r_) * 1024 + c_ * 8;
    const ushort_t* pB0 = Wb + (size_t)(n0 +   0 + r_) * 1024 + c_ * 8;
    const ushort_t* pB1 = Wb + (size_t)(n0 +  64 + r_) * 1024 + c_ * 8;
    const ushort_t* pB2 = Wb + (size_t)(n0 + 128 + r_) * 1024 + c_ * 8;
    const ushort_t* pB3 = Wb + (size_t)(n0 + 192 + r_) * 1024 + c_ * 8;
    char* stA0 = (char*)&As[0][0] + wave * 1024;     // + buf*32768 + unit*8192
    char* stB0 = (char*)&Bs[0][0] + wave * 1024;

    f32x4 acc[8][4];
#pragma unroll
    for (int i = 0; i < 8; ++i)
#pragma unroll
        for (int j = 0; j < 4; ++j) acc[i][j] = (f32x4)0.f;

    // prologue issue order (vmcnt ledger): B(0) x4, A(0) x4, B(1) x4
    glds16(pB0, stB0);          glds16(pB1, stB0 + 8192);
    glds16(pB2, stB0 + 16384);  glds16(pB3, stB0 + 24576);
    glds16(pA0, stA0);          glds16(pA1, stA0 + 8192);
    glds16(pA2, stA0 + 16384);  glds16(pA3, stA0 + 24576);
    glds16(pB0 + 64, stB0 + 32768);          glds16(pB1 + 64, stB0 + 32768 + 8192);
    glds16(pB2 + 64, stB0 + 32768 + 16384);  glds16(pB3 + 64, stB0 + 32768 + 24576);

#pragma unroll 2
    for (int t = 0; t < 16; ++t) {
        int cur = t & 1;
        const char* rdA = (const char*)&As[0][0] + cur * 32768;
        const char* rdB = (const char*)&Bs[0][0] + cur * 32768;
        char* sA = stA0 + (cur ^ 1) * 32768;   // A(t+1) -> other buffer
        char* sB = stB0 + cur * 32768;         // B(t+2) -> buf cur (free after B reads)
        int kA = (t + 1) << 6;
        int kB = (t + 2) << 6;

        // ---- entry: A(t),B(t) forced complete; B(t+1)'s 4 loads stay in flight
        if (t < 15) { asm volatile("s_waitcnt vmcnt(4)" ::: "memory"); }
        else        { asm volatile("s_waitcnt vmcnt(0)" ::: "memory"); }
        BAR();
        if (t < 15) {
            glds16(pA0 + kA, sA);          glds16(pA1 + kA, sA + 8192);
            glds16(pA2 + kA, sA + 16384);  glds16(pA3 + kA, sA + 24576);
        }
        short8 bfr[4][2];
#pragma unroll
        for (int ni = 0; ni < 4; ++ni) {
            int rb = ni * 16 + l16;
            bfr[ni][0] = *(const short8*)(rdB + wn * 8192 + (rb * 8 + ((quad    ) ^ (rb & 7))) * 16);
            bfr[ni][1] = *(const short8*)(rdB + wn * 8192 + (rb * 8 + ((quad + 4) ^ (rb & 7))) * 16);
        }
        asm volatile("s_waitcnt lgkmcnt(0)" ::: "memory");   // only B reads outstanding
        BAR();                                               // B region of buf cur now free
        if (t < 14) {
            glds16(pB0 + kB, sB);          glds16(pB1 + kB, sB + 8192);
            glds16(pB2 + kB, sB + 16384);  glds16(pB3 + kB, sB + 24576);
        }
        // A reads + MFMA, no barriers — compiler overlaps read latency with MFMAs
        __builtin_amdgcn_s_setprio(1);
#pragma unroll
        for (int mi = 0; mi < 8; ++mi) {
            int u = wm * 2 + (mi >> 2);
            int rr = (mi & 3) * 16 + l16;
            short8 a0 = *(const short8*)(rdA + u * 8192 + (rr * 8 + ((quad    ) ^ (rr & 7))) * 16);
            short8 a1 = *(const short8*)(rdA + u * 8192 + (rr * 8 + ((quad + 4) ^ (rr & 7))) * 16);
            acc[mi][0] = MFMA16(a0, bfr[0][0], acc[mi][0]);
            acc[mi][1] = MFMA16(a0, bfr[1][0], acc[mi][1]);
            acc[mi][2] = MFMA16(a0, bfr[2][0], acc[mi][2]);
            acc[mi][3] = MFMA16(a0, bfr[3][0], acc[mi][3]);
            acc[mi][0] = MFMA16(a1, bfr[0][1], acc[mi][0]);
            acc[mi][1] = MFMA16(a1, bfr[1][1], acc[mi][1]);
            acc[mi][2] = MFMA16(a1, bfr[2][1], acc[mi][2]);
            acc[mi][3] = MFMA16(a1, bfr[3][1], acc[mi][3]);
        }
        __builtin_amdgcn_s_setprio(0);
    }

    // epilogue: bias + lora + rope + scatter
    int t_qkv = n0 >> 10;        // 0=q 1=k 2=v, block-uniform (256 | 1024)
    int b = m0 >> 10;            // block-uniform
    int a_idx = adapter_mask[b];
    float bi[4], bb[4][4];
    int cpos[4], chh[4];
#pragma unroll
    for (int ni = 0; ni < 4; ++ni) {
        int c = n0 + wn * 64 + ni * 16 + l16;
        bi[ni] = bias[c];
        const float* Bp = loraB + ((size_t)a_idx * 3072 + c) * 4;
        bb[ni][0] = Bp[0]; bb[ni][1] = Bp[1]; bb[ni][2] = Bp[2]; bb[ni][3] = Bp[3];
        cpos[ni] = c & 63; chh[ni] = (c >> 6) & 15;
    }
#pragma unroll
    for (int mi = 0; mi < 8; ++mi) {
        float vals[4][4];   // [r][ni]
        int mrow0 = m0 + wm * 128 + mi * 16 + quad * 4;
#pragma unroll
        for (int r = 0; r < 4; ++r) {
            float4 lov = lo[mrow0 + r];
#pragma unroll
            for (int ni = 0; ni < 4; ++ni)
                vals[r][ni] = acc[mi][ni][r] + bi[ni]
                      + 0.25f * (lov.x * bb[ni][0] + lov.y * bb[ni][1]
                               + lov.z * bb[ni][2] + lov.w * bb[ni][3]);
        }
        int s0 = mrow0 & 1023;
        if (t_qkv < 2) {
#pragma unroll
            for (int r = 0; r < 4; ++r) {
                int s = s0 + r;
                size_t cb = ((size_t)b * 1024 + s) * 64;
                float cA = cosp[cb + l16],      sA_ = sinp[cb + l16];
                float cB = cosp[cb + 16 + l16], sB_ = sinp[cb + 16 + l16];
                float w0 = vals[r][0] * cA - vals[r][2] * sA_;
                float w2 = vals[r][2] * cA + vals[r][0] * sA_;
                float w1 = vals[r][1] * cB - vals[r][3] * sB_;
                float w3 = vals[r][3] * cB + vals[r][1] * sB_;
                float v[4] = {w0, w1, w2, w3};
#pragma unroll
                for (int ni = 0; ni < 4; ++ni) {
                    size_t bh = (size_t)b * 16 + chh[ni];
                    ushort_t ob = f2bf(v[ni]);
                    if (t_qkv == 0) qw[(bh * 1024 + s) * 64 + cpos[ni]] = ob;
                    else            kw[(bh * 1024 + s) * 64 + cpos[ni]] = ob;
                }
            }
        } else {
#pragma unroll
            for (int ni = 0; ni < 4; ++ni) {
                uint2 pk;
                pk.x = pack2(vals[0][ni], vals[1][ni]);
                pk.y = pack2(vals[2][ni], vals[3][ni]);
                size_t bh = (size_t)b * 16 + chh[ni];
                *(uint2*)&vt[(bh * 64 + cpos[ni]) * 1024 + s0] = pk;
            }
        }
    }
}

// ---------------- kernel 3: attention — triple-buffered K/V, prefetch depth 2, counted vmcnt ----
__global__ __launch_bounds__(256) void attn_kernel(
    const ushort_t* __restrict__ qw,   // (B,H,S,hd) bf16 (rope applied)
    const ushort_t* __restrict__ kw,   // (B,H,S,hd) bf16 (rope applied)
    const ushort_t* __restrict__ vt,   // (B,H,hd,S) bf16
    const float* __restrict__ mask,    // (B,1,1,S) f32
    float* __restrict__ out)           // (B,S,H*hd) f32
{
    __shared__ __align__(16) ushort_t Kt[3][4096];    // 8KB per buf, 24KB
    __shared__ __align__(16) ushort_t Vt[3][4096];    // 24KB
    __shared__ __align__(16) ushort_t Ps[4][32][72];  // per-wave, 18KB
    __shared__ float mlds[1024];                      // 4KB  (total 70KB -> 2 blk/CU)
    const float KSCALE = 0.125f * 1.44269504f;
    int tid = threadIdx.x;
    int wave = tid >> 6, lane = tid & 63, quad = lane >> 4, l16 = lane & 15;
    int id = blockIdx.x;
    int qt = id >> 7;             // 0..7
    int bh = id & 127;            // 0..127
    int b = bh >> 4, h = bh & 15;
    size_t base = (size_t)bh * 65536;
    int q0 = qt * 128 + wave * 32;

    for (int i = tid; i < 1024; i += 256) mlds[i] = mask[b * 1024 + i] * 1.44269504f;

    const ushort_t* kbase = kw + base;
    const ushort_t* vbase = vt + base;

    int n0 = tid, n1 = tid + 256;
    int r0 = n0 >> 3, c0 = (n0 & 7) ^ (r0 & 7);
    int r1 = n1 >> 3, c1 = (n1 & 7) ^ (r1 & 7);

    short8 qf[2][2];
    for (int mt = 0; mt < 2; ++mt)
        for (int kt = 0; kt < 2; ++kt)
            qf[mt][kt] = *(const short8*)(qw + base + (size_t)(q0 + mt * 16 + l16) * 64 + kt * 32 + quad * 8);

    f32x4 oacc[2][4], sum_acc[2];
    for (int mt = 0; mt < 2; ++mt) {
        sum_acc[mt] = (f32x4)0.f;
        for (int nt = 0; nt < 4; ++nt) oacc[mt][nt] = (f32x4)0.f;
    }

    short8 ones;
    for (int j = 0; j < 8; ++j) ones[j] = (short)0x3F80;   // bf16 1.0

    __syncthreads();

    int koff[4][2], voff[4][2];
    for (int nt = 0; nt < 4; ++nt)
        for (int kt = 0; kt < 2; ++kt) {
            int rr = nt * 16 + l16;
            int cc = (kt * 4 + quad) ^ (rr & 7);
            koff[nt][kt] = (rr * 8 + cc) * 8;
            voff[nt][kt] = (rr * 8 + cc) * 8;
        }

    {
        char* kd = (char*)&Kt[0][0] + wave * 1024;
        char* vd = (char*)&Vt[0][0] + wave * 1024;
        glds16(kbase + (size_t)r0 * 64 + c0 * 8, kd);
        glds16(kbase + (size_t)r1 * 64 + c1 * 8, kd + 4096);
        glds16(vbase + (size_t)r0 * 1024 + c0 * 8, vd);
        glds16(vbase + (size_t)r1 * 1024 + c1 * 8, vd + 4096);
        kd = (char*)&Kt[1][0] + wave * 1024;
        vd = (char*)&Vt[1][0] + wave * 1024;
        glds16(kbase + (size_t)(64 + r0) * 64 + c0 * 8, kd);
        glds16(kbase + (size_t)(64 + r1) * 64 + c1 * 8, kd + 4096);
        glds16(vbase + (size_t)r0 * 1024 + 64 + c0 * 8, vd);
        glds16(vbase + (size_t)r1 * 1024 + 64 + c1 * 8, vd + 4096);
    }

    const ushort_t* kR  = &Kt[0][0];  const ushort_t* vR  = &Vt[0][0];
    const ushort_t* kN1 = &Kt[1][0];  const ushort_t* vN1 = &Vt[1][0];
    const ushort_t* kN2 = &Kt[2][0];  const ushort_t* vN2 = &Vt[2][0];

    for (int it = 0; it < 16; ++it) {
        int kt0 = it * 64;
        if (it < 15) { asm volatile("s_waitcnt vmcnt(4)" ::: "memory"); }
        else         { asm volatile("s_waitcnt vmcnt(0)" ::: "memory"); }
        BAR();
        __builtin_amdgcn_sched_barrier(0);
        if (it < 14) {
            int kn = kt0 + 128;
            char* kd = (char*)kN2 + wave * 1024;
            char* vd = (char*)vN2 + wave * 1024;
            glds16(kbase + (size_t)(kn + r0) * 64 + c0 * 8, kd);
            glds16(kbase + (size_t)(kn + r1) * 64 + c1 * 8, kd + 4096);
            glds16(vbase + (size_t)r0 * 1024 + kn + c0 * 8, vd);
            glds16(vbase + (size_t)r1 * 1024 + kn + c1 * 8, vd + 4096);
        }
        short8 kf[4][2];
        for (int nt = 0; nt < 4; ++nt)
            for (int kt = 0; kt < 2; ++kt)
                kf[nt][kt] = *(const short8*)&kR[koff[nt][kt]];
        f32x4 sacc[2][4];
        for (int mt = 0; mt < 2; ++mt)
            for (int nt = 0; nt < 4; ++nt) {
                f32x4 z = (f32x4)0.f;
                z = MFMA16(qf[mt][0], kf[nt][0], z);
                z = MFMA16(qf[mt][1], kf[nt][1], z);
                sacc[mt][nt] = z;
            }
        float mv[4];
        for (int nt = 0; nt < 4; ++nt) mv[nt] = mlds[kt0 + nt * 16 + l16];
        for (int mt = 0; mt < 2; ++mt)
            for (int nt = 0; nt < 4; ++nt)
                for (int r = 0; r < 4; ++r) {
                    float p = EXP2F(sacc[mt][nt][r] * KSCALE + mv[nt]);
                    Ps[wave][mt * 16 + quad * 4 + r][nt * 16 + l16] = f2bf(p);
                }
        short8 pf[2][2];
        for (int mt = 0; mt < 2; ++mt)
            for (int kt = 0; kt < 2; ++kt)
                pf[mt][kt] = *(const short8*)&Ps[wave][mt * 16 + l16][kt * 32 + quad * 8];
        short8 vf[4][2];
        for (int nt = 0; nt < 4; ++nt)
            for (int kt = 0; kt < 2; ++kt)
                vf[nt][kt] = *(const short8*)&vR[voff[nt][kt]];
        for (int mt = 0; mt < 2; ++mt) {
            for (int nt = 0; nt < 4; ++nt) {
                oacc[mt][nt] = MFMA16(pf[mt][0], vf[nt][0], oacc[mt][nt]);
                oacc[mt][nt] = MFMA16(pf[mt][1], vf[nt][1], oacc[mt][nt]);
            }
            sum_acc[mt] = MFMA16(pf[mt][0], ones, sum_acc[mt]);
            sum_acc[mt] = MFMA16(pf[mt][1], ones, sum_acc[mt]);
        }
        const ushort_t* tk = kR; kR = kN1; kN1 = kN2; kN2 = tk;
        const ushort_t* tv = vR; vR = vN1; vN1 = vN2; vN2 = tv;
    }

    for (int mt = 0; mt < 2; ++mt) {
        for (int r = 0; r < 4; ++r) {
            float inv = 1.f / sum_acc[mt][r];
            int s = q0 + mt * 16 + quad * 4 + r;
            size_t ob = ((size_t)b * 1024 + s) * 1024 + h * 64;
            for (int nt = 0; nt < 4; ++nt)
                out[ob + nt * 16 + l16] = oacc[mt][nt][r] * inv;
        }
    }
}

extern "C" void kernel_launch(void* const* d_in, const int* in_sizes, int n_in,
                              void* d_out, int out_size, void* d_ws, size_t ws_size,
                              hipStream_t stream)
{
    const float* hidden = (const float*)d_in[0];
    const float* mask   = (const float*)d_in[1];
    const float* cosp   = (const float*)d_in[2];
    const float* sinp   = (const float*)d_in[3];
    const int* adapter_mask = (const int*)d_in[4];
    const float* W      = (const float*)d_in[5];
    const float* bias   = (const float*)d_in[6];
    const float* loraA  = (const float*)d_in[7];
    const float* loraB  = (const float*)d_in[8];
    float* out = (float*)d_out;

    char* ws = (char*)d_ws;
    float4* lo = (float4*)ws;                                  // 128 KB
    ushort_t* qw = (ushort_t*)(ws + (1 << 20));                // 16 MB each
    ushort_t* kw = qw + (size_t)8 * 16 * 1024 * 64;
    ushort_t* vt = kw + (size_t)8 * 16 * 1024 * 64;            // total 49 MB (proven fits)

    ushort_t* Hb = (ushort_t*)d_out;                           // 16 MB
    ushort_t* Wb = Hb + (size_t)8192 * 1024;                   // 6 MB

    prep_kernel<<<2816, 256, 0, stream>>>(hidden, W, loraA, adapter_mask, Hb, Wb, lo);
    qkv_gemm_kernel<<<384, 512, 0, stream>>>(Hb, Wb, bias, lo, loraB, adapter_mask,
                                             cosp, sinp, qw, kw, vt);
    attn_kernel<<<1024, 256, 0, stream>>>(qw, kw, vt, mask, out);
}

// Round 8
// 236.351 us; speedup vs baseline: 1.4217x; 1.0404x over previous
//
#include <hip/hip_runtime.h>
#include <hip/hip_bf16.h>
#include <stdint.h>

typedef __attribute__((ext_vector_type(8))) short short8;
typedef __attribute__((ext_vector_type(4))) float f32x4;
typedef unsigned short ushort_t;

#define MFMA16(a, b, c) __builtin_amdgcn_mfma_f32_16x16x32_bf16((a), (b), (c), 0, 0, 0)
#define EXP2F(x) __builtin_amdgcn_exp2f(x)
#define BAR() __builtin_amdgcn_s_barrier()

// B=8 S=1024 D=1024 H=16 hd=64; M = B*S = 8192; N = 3*D = 3072; K = 1024

__device__ __forceinline__ float bf2f(unsigned short u) {
    union { unsigned int i; float f; } x; x.i = ((unsigned int)u) << 16; return x.f;
}
__device__ __forceinline__ unsigned short f2bf(float f) {
    union { float f; unsigned int i; } x; x.f = f;
    unsigned int i = x.i;
    i = i + 0x7FFFu + ((i >> 16) & 1u);   // RNE
    return (unsigned short)(i >> 16);
}
__device__ __forceinline__ unsigned int pack2(float a, float b) {
    return (unsigned int)f2bf(a) | ((unsigned int)f2bf(b) << 16);
}
__device__ __forceinline__ void glds16(const void* gsrc, void* ldst) {
    __builtin_amdgcn_global_load_lds(
        (const __attribute__((address_space(1))) unsigned int*)gsrc,
        (__attribute__((address_space(3))) unsigned int*)ldst, 16, 0, 0);
}

// ---------------- kernel 1: fused prep v2 — per-instruction coalesced ----------------
__global__ __launch_bounds__(256) void prep_kernel(
    const float* __restrict__ hidden,   // (8192,1024)
    const float* __restrict__ W,        // (3072,1024)
    const float* __restrict__ loraA,    // (5,4,1024)
    const int* __restrict__ adapter_mask,
    ushort_t* __restrict__ Hb,
    ushort_t* __restrict__ Wb,
    float4* __restrict__ lo)
{
    int tid = threadIdx.x;
    int wave = tid >> 6, lane = tid & 63;
    int row = blockIdx.x * 4 + wave;     // 0..11263
    if (row < 8192) {
        int b = row >> 10;
        int a = adapter_mask[b];
        const float4* hp = (const float4*)(hidden + (size_t)row * 1024);
        float4 hv[4];
#pragma unroll
        for (int c = 0; c < 4; ++c) hv[c] = hp[c * 64 + lane];
#pragma unroll
        for (int c = 0; c < 4; ++c) {
            uint2 pk;
            pk.x = pack2(hv[c].x, hv[c].y);
            pk.y = pack2(hv[c].z, hv[c].w);
            *(uint2*)(Hb + (size_t)row * 1024 + c * 256 + lane * 4) = pk;
        }
        const float4* Ap = (const float4*)(loraA + (size_t)a * 4096);
        float acc[4];
#pragma unroll
        for (int r = 0; r < 4; ++r) {
            float s = 0.f;
#pragma unroll
            for (int c = 0; c < 4; ++c) {
                float4 av = Ap[(size_t)r * 256 + c * 64 + lane];
                s += hv[c].x * av.x + hv[c].y * av.y + hv[c].z * av.z + hv[c].w * av.w;
            }
            acc[r] = s;
        }
        for (int off = 32; off > 0; off >>= 1)
#pragma unroll
            for (int r = 0; r < 4; ++r) acc[r] += __shfl_xor(acc[r], off);
        if (lane == 0) lo[row] = make_float4(acc[0], acc[1], acc[2], acc[3]);
    } else {
        int rw = row - 8192;             // 0..3071
        const float4* wp = (const float4*)(W + (size_t)rw * 1024);
        float4 wv[4];
#pragma unroll
        for (int c = 0; c < 4; ++c) wv[c] = wp[c * 64 + lane];
#pragma unroll
        for (int c = 0; c < 4; ++c) {
            uint2 pk;
            pk.x = pack2(wv[c].x, wv[c].y);
            pk.y = pack2(wv[c].z, wv[c].w);
            *(uint2*)(Wb + (size_t)rw * 1024 + c * 256 + lane * 4) = pk;
        }
    }
}

// ---------------- kernel 2: qkv GEMM (round-4 version, best measured — frozen) ----------
__global__ __launch_bounds__(512, 2) void qkv_gemm_kernel(
    const ushort_t* __restrict__ Hb,   // (8192,1024) bf16
    const ushort_t* __restrict__ Wb,   // (3072,1024) bf16
    const float* __restrict__ bias,    // (3072)
    const float4* __restrict__ lo,     // (8192)
    const float* __restrict__ loraB,   // (5,3072,4)
    const int* __restrict__ adapter_mask, // (8)
    const float* __restrict__ cosp,    // (8,1024,64)
    const float* __restrict__ sinp,
    ushort_t* __restrict__ qw,
    ushort_t* __restrict__ kw,
    ushort_t* __restrict__ vt)
{
    __shared__ __align__(16) ushort_t As[2][16384];   // 64 KB
    __shared__ __align__(16) ushort_t Bs[2][16384];   // 64 KB
    int tid = threadIdx.x;
    int wave = tid >> 6, lane = tid & 63, quad = lane >> 4, l16 = lane & 15;
    int wm = wave >> 2, wn = wave & 3;               // 2M x 4N

    // bijective XCD swizzle: 384 blocks = 8 * 48
    int wg = (blockIdx.x & 7) * 48 + (blockIdx.x >> 3);
    int bx = wg % 12, by = wg / 12;
    int n0 = bx * 256;
    int m0 = by * 256;

    int r_ = tid >> 3, c_ = (tid & 7) ^ (r_ & 7);
    const ushort_t* pA0 = Hb + (size_t)(m0 +   0 + r_) * 1024 + c_ * 8;
    const ushort_t* pA1 = Hb + (size_t)(m0 +  64 + r_) * 1024 + c_ * 8;
    const ushort_t* pA2 = Hb + (size_t)(m0 + 128 + r_) * 1024 + c_ * 8;
    const ushort_t* pA3 = Hb + (size_t)(m0 + 192 + r_) * 1024 + c_ * 8;
    const ushort_t* pB0 = Wb + (size_t)(n0 +   0 + r_) * 1024 + c_ * 8;
    const ushort_t* pB1 = Wb + (size_t)(n0 +  64 + r_) * 1024 + c_ * 8;
    const ushort_t* pB2 = Wb + (size_t)(n0 + 128 + r_) * 1024 + c_ * 8;
    const ushort_t* pB3 = Wb + (size_t)(n0 + 192 + r_) * 1024 + c_ * 8;
    char* stA0 = (char*)&As[0][0] + wave * 1024;     // + buf*32768 + unit*8192
    char* stB0 = (char*)&Bs[0][0] + wave * 1024;

    f32x4 acc[8][4];
#pragma unroll
    for (int i = 0; i < 8; ++i)
#pragma unroll
        for (int j = 0; j < 4; ++j) acc[i][j] = (f32x4)0.f;

    // prologue issue order (vmcnt ledger): B(0) x4, A(0) x4, B(1) x4
    glds16(pB0, stB0);          glds16(pB1, stB0 + 8192);
    glds16(pB2, stB0 + 16384);  glds16(pB3, stB0 + 24576);
    glds16(pA0, stA0);          glds16(pA1, stA0 + 8192);
    glds16(pA2, stA0 + 16384);  glds16(pA3, stA0 + 24576);
    glds16(pB0 + 64, stB0 + 32768);          glds16(pB1 + 64, stB0 + 32768 + 8192);
    glds16(pB2 + 64, stB0 + 32768 + 16384);  glds16(pB3 + 64, stB0 + 32768 + 24576);

#pragma unroll 2
    for (int t = 0; t < 16; ++t) {
        int cur = t & 1;
        const char* rdA = (const char*)&As[0][0] + cur * 32768;
        const char* rdB = (const char*)&Bs[0][0] + cur * 32768;
        char* sA = stA0 + (cur ^ 1) * 32768;   // A(t+1) -> other buffer
        char* sB = stB0 + cur * 32768;         // B(t+2) -> buf cur (free after B reads)
        int kA = (t + 1) << 6;
        int kB = (t + 2) << 6;

        // ---- entry: A(t),B(t) forced complete; B(t+1)'s 4 loads stay in flight
        if (t < 15) { asm volatile("s_waitcnt vmcnt(4)" ::: "memory"); }
        else        { asm volatile("s_waitcnt vmcnt(0)" ::: "memory"); }
        BAR();
        if (t < 15) {
            glds16(pA0 + kA, sA);          glds16(pA1 + kA, sA + 8192);
            glds16(pA2 + kA, sA + 16384);  glds16(pA3 + kA, sA + 24576);
        }
        short8 bfr[4][2];
#pragma unroll
        for (int ni = 0; ni < 4; ++ni) {
            int rb = ni * 16 + l16;
            bfr[ni][0] = *(const short8*)(rdB + wn * 8192 + (rb * 8 + ((quad    ) ^ (rb & 7))) * 16);
            bfr[ni][1] = *(const short8*)(rdB + wn * 8192 + (rb * 8 + ((quad + 4) ^ (rb & 7))) * 16);
        }
        asm volatile("s_waitcnt lgkmcnt(0)" ::: "memory");   // only B reads outstanding
        BAR();                                               // B region of buf cur now free
        if (t < 14) {
            glds16(pB0 + kB, sB);          glds16(pB1 + kB, sB + 8192);
            glds16(pB2 + kB, sB + 16384);  glds16(pB3 + kB, sB + 24576);
        }
        // A reads + MFMA, no barriers — compiler overlaps read latency with MFMAs
        __builtin_amdgcn_s_setprio(1);
#pragma unroll
        for (int mi = 0; mi < 8; ++mi) {
            int u = wm * 2 + (mi >> 2);
            int rr = (mi & 3) * 16 + l16;
            short8 a0 = *(const short8*)(rdA + u * 8192 + (rr * 8 + ((quad    ) ^ (rr & 7))) * 16);
            short8 a1 = *(const short8*)(rdA + u * 8192 + (rr * 8 + ((quad + 4) ^ (rr & 7))) * 16);
            acc[mi][0] = MFMA16(a0, bfr[0][0], acc[mi][0]);
            acc[mi][1] = MFMA16(a0, bfr[1][0], acc[mi][1]);
            acc[mi][2] = MFMA16(a0, bfr[2][0], acc[mi][2]);
            acc[mi][3] = MFMA16(a0, bfr[3][0], acc[mi][3]);
            acc[mi][0] = MFMA16(a1, bfr[0][1], acc[mi][0]);
            acc[mi][1] = MFMA16(a1, bfr[1][1], acc[mi][1]);
            acc[mi][2] = MFMA16(a1, bfr[2][1], acc[mi][2]);
            acc[mi][3] = MFMA16(a1, bfr[3][1], acc[mi][3]);
        }
        __builtin_amdgcn_s_setprio(0);
    }

    // epilogue: bias + lora + rope + scatter
    int t_qkv = n0 >> 10;        // 0=q 1=k 2=v, block-uniform (256 | 1024)
    int b = m0 >> 10;            // block-uniform
    int a_idx = adapter_mask[b];
    float bi[4], bb[4][4];
    int cpos[4], chh[4];
#pragma unroll
    for (int ni = 0; ni < 4; ++ni) {
        int c = n0 + wn * 64 + ni * 16 + l16;
        bi[ni] = bias[c];
        const float* Bp = loraB + ((size_t)a_idx * 3072 + c) * 4;
        bb[ni][0] = Bp[0]; bb[ni][1] = Bp[1]; bb[ni][2] = Bp[2]; bb[ni][3] = Bp[3];
        cpos[ni] = c & 63; chh[ni] = (c >> 6) & 15;
    }
#pragma unroll
    for (int mi = 0; mi < 8; ++mi) {
        float vals[4][4];   // [r][ni]
        int mrow0 = m0 + wm * 128 + mi * 16 + quad * 4;
#pragma unroll
        for (int r = 0; r < 4; ++r) {
            float4 lov = lo[mrow0 + r];
#pragma unroll
            for (int ni = 0; ni < 4; ++ni)
                vals[r][ni] = acc[mi][ni][r] + bi[ni]
                      + 0.25f * (lov.x * bb[ni][0] + lov.y * bb[ni][1]
                               + lov.z * bb[ni][2] + lov.w * bb[ni][3]);
        }
        int s0 = mrow0 & 1023;
        if (t_qkv < 2) {
#pragma unroll
            for (int r = 0; r < 4; ++r) {
                int s = s0 + r;
                size_t cb = ((size_t)b * 1024 + s) * 64;
                float cA = cosp[cb + l16],      sA_ = sinp[cb + l16];
                float cB = cosp[cb + 16 + l16], sB_ = sinp[cb + 16 + l16];
                float w0 = vals[r][0] * cA - vals[r][2] * sA_;
                float w2 = vals[r][2] * cA + vals[r][0] * sA_;
                float w1 = vals[r][1] * cB - vals[r][3] * sB_;
                float w3 = vals[r][3] * cB + vals[r][1] * sB_;
                float v[4] = {w0, w1, w2, w3};
#pragma unroll
                for (int ni = 0; ni < 4; ++ni) {
                    size_t bh = (size_t)b * 16 + chh[ni];
                    ushort_t ob = f2bf(v[ni]);
                    if (t_qkv == 0) qw[(bh * 1024 + s) * 64 + cpos[ni]] = ob;
                    else            kw[(bh * 1024 + s) * 64 + cpos[ni]] = ob;
                }
            }
        } else {
#pragma unroll
            for (int ni = 0; ni < 4; ++ni) {
                uint2 pk;
                pk.x = pack2(vals[0][ni], vals[1][ni]);
                pk.y = pack2(vals[2][ni], vals[3][ni]);
                size_t bh = (size_t)b * 16 + chh[ni];
                *(uint2*)&vt[(bh * 64 + cpos[ni]) * 1024 + s0] = pk;
            }
        }
    }
}

// ---------------- kernel 3: attention v3 — 2 q-tiles per block (512 blocks) ----------
// Same triple-buffered K/V + counted vmcnt as round 3, but each block computes
// 256 q-rows (two 128-row tiles at q0 and q0+128) against the SAME staged K/V:
// halves the per-unit-compute staging/barrier/DMA cost and the block rounds
// (512 blocks = 2/CU, one residency round). kf/vf are scoped per phase so
// registers are reused (VGPR ~200, __launch_bounds__(256,2)). Ps reused across
// the two phases (per-wave private; same-wave LDS deps compiler-ordered).
__global__ __launch_bounds__(256, 2) void attn_kernel(
    const ushort_t* __restrict__ qw,   // (B,H,S,hd) bf16 (rope applied)
    const ushort_t* __restrict__ kw,   // (B,H,S,hd) bf16 (rope applied)
    const ushort_t* __restrict__ vt,   // (B,H,hd,S) bf16
    const float* __restrict__ mask,    // (B,1,1,S) f32
    float* __restrict__ out)           // (B,S,H*hd) f32
{
    __shared__ __align__(16) ushort_t Kt[3][4096];    // 24KB
    __shared__ __align__(16) ushort_t Vt[3][4096];    // 24KB
    __shared__ __align__(16) ushort_t Ps[4][32][72];  // 18KB (per-wave)
    __shared__ float mlds[1024];                      // 4KB  (total 70KB -> 2 blk/CU)
    const float KSCALE = 0.125f * 1.44269504f;
    int tid = threadIdx.x;
    int wave = tid >> 6, lane = tid & 63, quad = lane >> 4, l16 = lane & 15;
    int id = blockIdx.x;
    int qp = id >> 7;             // 0..3 (256 q-rows each)
    int bh = id & 127;            // 0..127 (id%8 == bh%8 -> XCD-local K/V)
    int b = bh >> 4, h = bh & 15;
    size_t base = (size_t)bh * 65536;
    int q0 = qp * 256 + wave * 32;          // phase 0 rows; phase 1: +128

    for (int i = tid; i < 1024; i += 256) mlds[i] = mask[b * 1024 + i] * 1.44269504f;

    const ushort_t* kbase = kw + base;
    const ushort_t* vbase = vt + base;

    int n0 = tid, n1 = tid + 256;
    int r0 = n0 >> 3, c0 = (n0 & 7) ^ (r0 & 7);
    int r1 = n1 >> 3, c1 = (n1 & 7) ^ (r1 & 7);

    // Q fragments for both q-tiles: mt 0,1 -> q0+mt*16; mt 2,3 -> q0+128+(mt-2)*16
    short8 qf[4][2];
    for (int mt = 0; mt < 4; ++mt) {
        int qr = q0 + (mt >> 1) * 128 + (mt & 1) * 16;
        for (int kt = 0; kt < 2; ++kt)
            qf[mt][kt] = *(const short8*)(qw + base + (size_t)(qr + l16) * 64 + kt * 32 + quad * 8);
    }

    f32x4 oacc[4][4], sum_acc[4];
    for (int mt = 0; mt < 4; ++mt) {
        sum_acc[mt] = (f32x4)0.f;
        for (int nt = 0; nt < 4; ++nt) oacc[mt][nt] = (f32x4)0.f;
    }

    short8 ones;
    for (int j = 0; j < 8; ++j) ones[j] = (short)0x3F80;   // bf16 1.0

    __syncthreads();   // mlds visible (one-time; no staging outstanding yet)

    int koff[4][2], voff[4][2];
    for (int nt = 0; nt < 4; ++nt)
        for (int kt = 0; kt < 2; ++kt) {
            int rr = nt * 16 + l16;
            int cc = (kt * 4 + quad) ^ (rr & 7);
            koff[nt][kt] = (rr * 8 + cc) * 8;
            voff[nt][kt] = (rr * 8 + cc) * 8;
        }

    {
        char* kd = (char*)&Kt[0][0] + wave * 1024;
        char* vd = (char*)&Vt[0][0] + wave * 1024;
        glds16(kbase + (size_t)r0 * 64 + c0 * 8, kd);
        glds16(kbase + (size_t)r1 * 64 + c1 * 8, kd + 4096);
        glds16(vbase + (size_t)r0 * 1024 + c0 * 8, vd);
        glds16(vbase + (size_t)r1 * 1024 + c1 * 8, vd + 4096);
        kd = (char*)&Kt[1][0] + wave * 1024;
        vd = (char*)&Vt[1][0] + wave * 1024;
        glds16(kbase + (size_t)(64 + r0) * 64 + c0 * 8, kd);
        glds16(kbase + (size_t)(64 + r1) * 64 + c1 * 8, kd + 4096);
        glds16(vbase + (size_t)r0 * 1024 + 64 + c0 * 8, vd);
        glds16(vbase + (size_t)r1 * 1024 + 64 + c1 * 8, vd + 4096);
    }

    const ushort_t* kR  = &Kt[0][0];  const ushort_t* vR  = &Vt[0][0];
    const ushort_t* kN1 = &Kt[1][0];  const ushort_t* vN1 = &Vt[1][0];
    const ushort_t* kN2 = &Kt[2][0];  const ushort_t* vN2 = &Vt[2][0];

    for (int it = 0; it < 16; ++it) {
        int kt0 = it * 64;
        if (it < 15) { asm volatile("s_waitcnt vmcnt(4)" ::: "memory"); }
        else         { asm volatile("s_waitcnt vmcnt(0)" ::: "memory"); }
        BAR();
        __builtin_amdgcn_sched_barrier(0);
        if (it < 14) {
            int kn = kt0 + 128;
            char* kd = (char*)kN2 + wave * 1024;
            char* vd = (char*)vN2 + wave * 1024;
            glds16(kbase + (size_t)(kn + r0) * 64 + c0 * 8, kd);
            glds16(kbase + (size_t)(kn + r1) * 64 + c1 * 8, kd + 4096);
            glds16(vbase + (size_t)r0 * 1024 + kn + c0 * 8, vd);
            glds16(vbase + (size_t)r1 * 1024 + kn + c1 * 8, vd + 4096);
        }
        float mv[4];
        for (int nt = 0; nt < 4; ++nt) mv[nt] = mlds[kt0 + nt * 16 + l16];

#pragma unroll
        for (int ph = 0; ph < 2; ++ph) {
            // S = Q K^T for this q-tile (kf scoped -> regs reused across phases)
            f32x4 sacc[2][4];
            {
                short8 kf[4][2];
#pragma unroll
                for (int nt = 0; nt < 4; ++nt)
#pragma unroll
                    for (int kt = 0; kt < 2; ++kt)
                        kf[nt][kt] = *(const short8*)&kR[koff[nt][kt]];
#pragma unroll
                for (int mt = 0; mt < 2; ++mt)
#pragma unroll
                    for (int nt = 0; nt < 4; ++nt) {
                        f32x4 z = (f32x4)0.f;
                        z = MFMA16(qf[ph * 2 + mt][0], kf[nt][0], z);
                        z = MFMA16(qf[ph * 2 + mt][1], kf[nt][1], z);
                        sacc[mt][nt] = z;
                    }
            }
#pragma unroll
            for (int mt = 0; mt < 2; ++mt)
#pragma unroll
                for (int nt = 0; nt < 4; ++nt)
#pragma unroll
                    for (int r = 0; r < 4; ++r) {
                        float p = EXP2F(sacc[mt][nt][r] * KSCALE + mv[nt]);
                        Ps[wave][mt * 16 + quad * 4 + r][nt * 16 + l16] = f2bf(p);
                    }
            short8 pf[2][2];
#pragma unroll
            for (int mt = 0; mt < 2; ++mt)
#pragma unroll
                for (int kt = 0; kt < 2; ++kt)
                    pf[mt][kt] = *(const short8*)&Ps[wave][mt * 16 + l16][kt * 32 + quad * 8];
            {
                short8 vf[4][2];
#pragma unroll
                for (int nt = 0; nt < 4; ++nt)
#pragma unroll
                    for (int kt = 0; kt < 2; ++kt)
                        vf[nt][kt] = *(const short8*)&vR[voff[nt][kt]];
#pragma unroll
                for (int mt = 0; mt < 2; ++mt) {
#pragma unroll
                    for (int nt = 0; nt < 4; ++nt) {
                        oacc[ph * 2 + mt][nt] = MFMA16(pf[mt][0], vf[nt][0], oacc[ph * 2 + mt][nt]);
                        oacc[ph * 2 + mt][nt] = MFMA16(pf[mt][1], vf[nt][1], oacc[ph * 2 + mt][nt]);
                    }
                    sum_acc[ph * 2 + mt] = MFMA16(pf[mt][0], ones, sum_acc[ph * 2 + mt]);
                    sum_acc[ph * 2 + mt] = MFMA16(pf[mt][1], ones, sum_acc[ph * 2 + mt]);
                }
            }
        }
        const ushort_t* tk = kR; kR = kN1; kN1 = kN2; kN2 = tk;
        const ushort_t* tv = vR; vR = vN1; vN1 = vN2; vN2 = tv;
    }

    for (int mt = 0; mt < 4; ++mt) {
        for (int r = 0; r < 4; ++r) {
            float inv = 1.f / sum_acc[mt][r];
            int s = q0 + (mt >> 1) * 128 + (mt & 1) * 16 + quad * 4 + r;
            size_t ob = ((size_t)b * 1024 + s) * 1024 + h * 64;
            for (int nt = 0; nt < 4; ++nt)
                out[ob + nt * 16 + l16] = oacc[mt][nt][r] * inv;
        }
    }
}

extern "C" void kernel_launch(void* const* d_in, const int* in_sizes, int n_in,
                              void* d_out, int out_size, void* d_ws, size_t ws_size,
                              hipStream_t stream)
{
    const float* hidden = (const float*)d_in[0];
    const float* mask   = (const float*)d_in[1];
    const float* cosp   = (const float*)d_in[2];
    const float* sinp   = (const float*)d_in[3];
    const int* adapter_mask = (const int*)d_in[4];
    const float* W      = (const float*)d_in[5];
    const float* bias   = (const float*)d_in[6];
    const float* loraA  = (const float*)d_in[7];
    const float* loraB  = (const float*)d_in[8];
    float* out = (float*)d_out;

    char* ws = (char*)d_ws;
    float4* lo = (float4*)ws;                                  // 128 KB
    ushort_t* qw = (ushort_t*)(ws + (1 << 20));                // 16 MB each
    ushort_t* kw = qw + (size_t)8 * 16 * 1024 * 64;
    ushort_t* vt = kw + (size_t)8 * 16 * 1024 * 64;            // total 49 MB (proven fits)

    ushort_t* Hb = (ushort_t*)d_out;                           // 16 MB
    ushort_t* Wb = Hb + (size_t)8192 * 1024;                   // 6 MB

    prep_kernel<<<2816, 256, 0, stream>>>(hidden, W, loraA, adapter_mask, Hb, Wb, lo);
    qkv_gemm_kernel<<<384, 512, 0, stream>>>(Hb, Wb, bias, lo, loraB, adapter_mask,
                                             cosp, sinp, qw, kw, vt);
    attn_kernel<<<512, 256, 0, stream>>>(qw, kw, vt, mask, out);
}